// Round 1
// baseline (1160.475 us; speedup 1.0000x reference)
//
#include <hip/hip_runtime.h>
#include <math.h>

#define T_DIM 2048
#define B_DIM 16
#define H_DIM 512
// out layout: results [T,B,2H] (33,554,432 floats) then attn [B,T,T] (67,108,864 floats)

// ---------------- Kernel 1: results = concat(inputs, ctx) ----------------
// ctx = inputs for t<2 else rand_ctx. All float4-vectorized.
__global__ __launch_bounds__(256) void k_results(const float4* __restrict__ in,
                                                 const float4* __restrict__ rc,
                                                 float4* __restrict__ out) {
    int i = blockIdx.x * 256 + threadIdx.x;   // over TB * 256 float4 (row = 1024 floats)
    int row = i >> 8;                          // t*B + b
    int c = i & 255;                           // float4 column in [0,256)
    int t = row >> 4;
    float4 v;
    if (c < 128) {
        v = in[row * 128 + c];
    } else {
        const float4* src = (t < 2) ? in : rc;
        v = src[row * 128 + (c - 128)];
    }
    out[i] = v;
}

// ---------------- Kernel 2: Q = X @ W  (M=32768, K=512, N=512) ----------------
// 64x64 tile per block, 256 threads, 4x4 micro-tile, BK=16.
__global__ __launch_bounds__(256) void k_qgemm(const float* __restrict__ X,
                                               const float* __restrict__ W,
                                               float* __restrict__ Q) {
    __shared__ float As[16][64];   // [kk][m]
    __shared__ float Bs[16][64];   // [kk][n]
    const int m0 = blockIdx.x * 64;
    const int n0 = blockIdx.y * 64;
    const int tid = threadIdx.x;
    const int ty = tid >> 4;       // m-group 0..15
    const int tx = tid & 15;       // n-group 0..15

    float acc[4][4] = {};

    for (int k0 = 0; k0 < H_DIM; k0 += 16) {
        // A tile: 64 rows x 16 k  (256 float4, one per thread)
        {
            int r = tid >> 2, kk = (tid & 3) * 4;
            float4 a = *(const float4*)&X[(size_t)(m0 + r) * H_DIM + k0 + kk];
            As[kk + 0][r] = a.x; As[kk + 1][r] = a.y;
            As[kk + 2][r] = a.z; As[kk + 3][r] = a.w;
            // B tile: 16 k-rows x 64 n (row-contiguous float4 store)
            int kr = tid >> 4, nn = (tid & 15) * 4;
            float4 b = *(const float4*)&W[(size_t)(k0 + kr) * H_DIM + n0 + nn];
            *(float4*)&Bs[kr][nn] = b;
        }
        __syncthreads();
#pragma unroll
        for (int kk = 0; kk < 16; ++kk) {
            float a[4], b[4];
#pragma unroll
            for (int i = 0; i < 4; ++i) a[i] = As[kk][ty * 4 + i];
#pragma unroll
            for (int j = 0; j < 4; ++j) b[j] = Bs[kk][tx * 4 + j];
#pragma unroll
            for (int i = 0; i < 4; ++i)
#pragma unroll
                for (int j = 0; j < 4; ++j) acc[i][j] += a[i] * b[j];
        }
        __syncthreads();
    }
#pragma unroll
    for (int i = 0; i < 4; ++i) {
        float4 v = {acc[i][0], acc[i][1], acc[i][2], acc[i][3]};
        *(float4*)&Q[(size_t)(m0 + ty * 4 + i) * H_DIM + n0 + tx * 4] = v;
    }
}

// ---------------- Kernel 3: scores[b,t,s] = Q[t,b,:] . X[s,b,:] ----------------
// NT GEMM per batch. 64x64 tiles; only lower-triangle tiles (s0 <= t0) computed,
// since softmax reads only s < t. Raw scores written into attn region.
__global__ __launch_bounds__(256) void k_scores(const float* __restrict__ Q,
                                                const float* __restrict__ X,
                                                float* __restrict__ attn) {
    const int t0 = blockIdx.x * 64;
    const int s0 = blockIdx.y * 64;
    if (s0 > t0) return;                    // tile never read downstream
    const int b = blockIdx.z;
    __shared__ float Qs[16][64];            // [kk][t]
    __shared__ float Xs[16][64];            // [kk][s]
    const int tid = threadIdx.x;
    const int ty = tid >> 4;                // t-group
    const int tx = tid & 15;                // s-group

    float acc[4][4] = {};

    for (int k0 = 0; k0 < H_DIM; k0 += 16) {
        {
            int r = tid >> 2, kk = (tid & 3) * 4;
            float4 a = *(const float4*)&Q[((size_t)(t0 + r) * B_DIM + b) * H_DIM + k0 + kk];
            Qs[kk + 0][r] = a.x; Qs[kk + 1][r] = a.y;
            Qs[kk + 2][r] = a.z; Qs[kk + 3][r] = a.w;
            float4 x = *(const float4*)&X[((size_t)(s0 + r) * B_DIM + b) * H_DIM + k0 + kk];
            Xs[kk + 0][r] = x.x; Xs[kk + 1][r] = x.y;
            Xs[kk + 2][r] = x.z; Xs[kk + 3][r] = x.w;
        }
        __syncthreads();
#pragma unroll
        for (int kk = 0; kk < 16; ++kk) {
            float a[4], x[4];
#pragma unroll
            for (int i = 0; i < 4; ++i) a[i] = Qs[kk][ty * 4 + i];
#pragma unroll
            for (int j = 0; j < 4; ++j) x[j] = Xs[kk][tx * 4 + j];
#pragma unroll
            for (int i = 0; i < 4; ++i)
#pragma unroll
                for (int j = 0; j < 4; ++j) acc[i][j] += a[i] * x[j];
        }
        __syncthreads();
    }
#pragma unroll
    for (int i = 0; i < 4; ++i) {
        float4 v = {acc[i][0], acc[i][1], acc[i][2], acc[i][3]};
        *(float4*)&attn[((size_t)b * T_DIM + (t0 + ty * 4 + i)) * T_DIM + s0 + tx * 4] = v;
    }
}

// ---------------- Kernel 4: in-place masked softmax per (b,t) row ----------------
__global__ __launch_bounds__(256) void k_softmax(float* __restrict__ attn) {
    const int row = blockIdx.x;             // b*T + t
    const int t = row & (T_DIM - 1);
    float* p = attn + (size_t)row * T_DIM;
    const int tid = threadIdx.x;
    const int n = (t >= 2) ? t : 0;         // valid s count
    __shared__ float red[4];

    if (n == 0) {
        const float4 z = {0.f, 0.f, 0.f, 0.f};
        for (int s = tid * 4; s < T_DIM; s += 1024) *(float4*)&p[s] = z;
        return;
    }

    // pass 1a: row max over s < n
    float m = -INFINITY;
    for (int s = tid; s < n; s += 256) m = fmaxf(m, p[s]);
#pragma unroll
    for (int off = 32; off >= 1; off >>= 1) m = fmaxf(m, __shfl_xor(m, off));
    if ((tid & 63) == 0) red[tid >> 6] = m;
    __syncthreads();
    m = fmaxf(fmaxf(red[0], red[1]), fmaxf(red[2], red[3]));
    __syncthreads();

    // pass 1b: sum of exp
    float sum = 0.f;
    for (int s = tid; s < n; s += 256) sum += expf(p[s] - m);
#pragma unroll
    for (int off = 32; off >= 1; off >>= 1) sum += __shfl_xor(sum, off);
    if ((tid & 63) == 0) red[tid >> 6] = sum;
    __syncthreads();
    sum = red[0] + red[1] + red[2] + red[3];
    const float inv = 1.f / sum;

    // pass 2: write normalized probs for s < n, zeros elsewhere (in-place safe:
    // this block owns the row; every thread re-reads before any write at its slot)
    for (int s = tid * 4; s < T_DIM; s += 1024) {
        float4 o = {0.f, 0.f, 0.f, 0.f};
        if (s + 3 < n) {
            float4 v = *(float4*)&p[s];
            o.x = expf(v.x - m) * inv;
            o.y = expf(v.y - m) * inv;
            o.z = expf(v.z - m) * inv;
            o.w = expf(v.w - m) * inv;
        } else if (s < n) {
            float tmp[4] = {0.f, 0.f, 0.f, 0.f};
            for (int j = 0; j < 4; ++j)
                if (s + j < n) tmp[j] = expf(p[s + j] - m) * inv;
            o.x = tmp[0]; o.y = tmp[1]; o.z = tmp[2]; o.w = tmp[3];
        }
        *(float4*)&p[s] = o;
    }
}

extern "C" void kernel_launch(void* const* d_in, const int* in_sizes, int n_in,
                              void* d_out, int out_size, void* d_ws, size_t ws_size,
                              hipStream_t stream) {
    const float* inputs   = (const float*)d_in[0];   // [T,B,H]
    const float* rand_ctx = (const float*)d_in[1];   // [T,B,H]
    const float* W        = (const float*)d_in[2];   // [H,H]
    float* out  = (float*)d_out;
    float* attn = out + (size_t)T_DIM * B_DIM * 2 * H_DIM;  // second output
    float* Q    = (float*)d_ws;                      // needs 32768*512*4 = 64 MB

    // 1) results copy/select: TB*256 float4 elements
    k_results<<<dim3((T_DIM * B_DIM * 256) / 256), dim3(256), 0, stream>>>(
        (const float4*)inputs, (const float4*)rand_ctx, (float4*)out);

    // 2) Q = X @ W
    k_qgemm<<<dim3((T_DIM * B_DIM) / 64, H_DIM / 64), dim3(256), 0, stream>>>(inputs, W, Q);

    // 3) raw scores (lower triangle tiles only)
    k_scores<<<dim3(T_DIM / 64, T_DIM / 64, B_DIM), dim3(256), 0, stream>>>(Q, inputs, attn);

    // 4) masked softmax in place
    k_softmax<<<dim3(B_DIM * T_DIM), dim3(256), 0, stream>>>(attn);
}

// Round 2
// 757.445 us; speedup vs baseline: 1.5321x; 1.5321x over previous
//
#include <hip/hip_runtime.h>
#include <math.h>

#define T_DIM 2048
#define B_DIM 16
#define H_DIM 512
// out layout: results [T,B,2H] (33,554,432 floats) then attn [B,T,T] (67,108,864 floats)

typedef short bf16x8 __attribute__((ext_vector_type(8)));
typedef float f32x4 __attribute__((ext_vector_type(4)));

__device__ __forceinline__ unsigned short f2bf(float x) {
    unsigned int u = __float_as_uint(x);
    u += 0x7FFFu + ((u >> 16) & 1u);
    return (unsigned short)(u >> 16);
}
__device__ __forceinline__ float bf2f(unsigned short h) {
    return __uint_as_float(((unsigned int)h) << 16);
}

// ---------------- Kernel 1: results = concat(inputs, ctx) ----------------
__global__ __launch_bounds__(256) void k_results(const float4* __restrict__ in,
                                                 const float4* __restrict__ rc,
                                                 float4* __restrict__ out) {
    int i = blockIdx.x * 256 + threadIdx.x;
    int row = i >> 8;
    int c = i & 255;
    int t = row >> 4;
    float4 v;
    if (c < 128) {
        v = in[row * 128 + c];
    } else {
        const float4* src = (t < 2) ? in : rc;
        v = src[row * 128 + (c - 128)];
    }
    out[i] = v;
}

// ---------------- Kernel 2: Q = X @ W  (M=32768, K=512, N=512), fp32 ----------------
__global__ __launch_bounds__(256) void k_qgemm(const float* __restrict__ X,
                                               const float* __restrict__ W,
                                               float* __restrict__ Q) {
    __shared__ float As[16][64];
    __shared__ float Bs[16][64];
    const int m0 = blockIdx.x * 64;
    const int n0 = blockIdx.y * 64;
    const int tid = threadIdx.x;
    const int ty = tid >> 4;
    const int tx = tid & 15;

    float acc[4][4] = {};

    for (int k0 = 0; k0 < H_DIM; k0 += 16) {
        {
            int r = tid >> 2, kk = (tid & 3) * 4;
            float4 a = *(const float4*)&X[(size_t)(m0 + r) * H_DIM + k0 + kk];
            As[kk + 0][r] = a.x; As[kk + 1][r] = a.y;
            As[kk + 2][r] = a.z; As[kk + 3][r] = a.w;
            int kr = tid >> 4, nn = (tid & 15) * 4;
            float4 b = *(const float4*)&W[(size_t)(k0 + kr) * H_DIM + n0 + nn];
            *(float4*)&Bs[kr][nn] = b;
        }
        __syncthreads();
#pragma unroll
        for (int kk = 0; kk < 16; ++kk) {
            float a[4], b[4];
#pragma unroll
            for (int i = 0; i < 4; ++i) a[i] = As[kk][ty * 4 + i];
#pragma unroll
            for (int j = 0; j < 4; ++j) b[j] = Bs[kk][tx * 4 + j];
#pragma unroll
            for (int i = 0; i < 4; ++i)
#pragma unroll
                for (int j = 0; j < 4; ++j) acc[i][j] += a[i] * b[j];
        }
        __syncthreads();
    }
#pragma unroll
    for (int i = 0; i < 4; ++i) {
        float4 v = {acc[i][0], acc[i][1], acc[i][2], acc[i][3]};
        *(float4*)&Q[(size_t)(m0 + ty * 4 + i) * H_DIM + n0 + tx * 4] = v;
    }
}

// ---------------- Kernel 3: scores via bf16 MFMA (Markidis hi/lo split) ----------------
// S[b,t,s] = Q[t,b,:].X[s,b,:] ~= qh.xh + ql.xh + qh.xl  (fp32 accumulate)
// 128x128 block tile, 4 waves of 64x64, BK=32, mfma_f32_16x16x32_bf16.
// LDS layout [g][row][8] (g = k-octet) so each fragment is one ds_read_b128.
__global__ __launch_bounds__(256) void k_scores_mfma(const float* __restrict__ Q,
                                                     const float* __restrict__ X,
                                                     float* __restrict__ attn) {
    const int t0 = blockIdx.x * 128;
    const int s0 = blockIdx.y * 128;
    if (s0 > t0) return;                 // softmax never reads s >= t
    const int b = blockIdx.z;

    __shared__ unsigned short Qh[4][128][8];
    __shared__ unsigned short Ql[4][128][8];
    __shared__ unsigned short Xh[4][128][8];
    __shared__ unsigned short Xl[4][128][8];

    const int tid = threadIdx.x;
    const int lane = tid & 63;
    const int w = tid >> 6;
    const int t_off = (w >> 1) * 64;
    const int s_off = (w & 1) * 64;
    const int l15 = lane & 15;
    const int lg = lane >> 4;

    f32x4 acc[4][4] = {};

    for (int k0 = 0; k0 < H_DIM; k0 += 32) {
        if (k0) __syncthreads();
        // stage + split: 2 Q-chunks + 2 X-chunks of 8 k-values per thread
#pragma unroll
        for (int p = 0; p < 2; ++p) {
            const int c = tid + p * 256;
            const int row = c & 127;
            const int g = c >> 7;
            {
                const float* src = &Q[(((size_t)(t0 + row)) * B_DIM + b) * H_DIM + k0 + g * 8];
                float4 v0 = *(const float4*)src;
                float4 v1 = *(const float4*)(src + 4);
                float xs[8] = {v0.x, v0.y, v0.z, v0.w, v1.x, v1.y, v1.z, v1.w};
                unsigned int hw[4], lw[4];
#pragma unroll
                for (int e = 0; e < 4; ++e) {
                    unsigned short h0 = f2bf(xs[2 * e]), h1 = f2bf(xs[2 * e + 1]);
                    unsigned short l0 = f2bf(xs[2 * e] - bf2f(h0));
                    unsigned short l1 = f2bf(xs[2 * e + 1] - bf2f(h1));
                    hw[e] = (unsigned int)h0 | ((unsigned int)h1 << 16);
                    lw[e] = (unsigned int)l0 | ((unsigned int)l1 << 16);
                }
                *(uint4*)&Qh[g][row][0] = make_uint4(hw[0], hw[1], hw[2], hw[3]);
                *(uint4*)&Ql[g][row][0] = make_uint4(lw[0], lw[1], lw[2], lw[3]);
            }
            {
                const float* src = &X[(((size_t)(s0 + row)) * B_DIM + b) * H_DIM + k0 + g * 8];
                float4 v0 = *(const float4*)src;
                float4 v1 = *(const float4*)(src + 4);
                float xs[8] = {v0.x, v0.y, v0.z, v0.w, v1.x, v1.y, v1.z, v1.w};
                unsigned int hw[4], lw[4];
#pragma unroll
                for (int e = 0; e < 4; ++e) {
                    unsigned short h0 = f2bf(xs[2 * e]), h1 = f2bf(xs[2 * e + 1]);
                    unsigned short l0 = f2bf(xs[2 * e] - bf2f(h0));
                    unsigned short l1 = f2bf(xs[2 * e + 1] - bf2f(h1));
                    hw[e] = (unsigned int)h0 | ((unsigned int)h1 << 16);
                    lw[e] = (unsigned int)l0 | ((unsigned int)l1 << 16);
                }
                *(uint4*)&Xh[g][row][0] = make_uint4(hw[0], hw[1], hw[2], hw[3]);
                *(uint4*)&Xl[g][row][0] = make_uint4(lw[0], lw[1], lw[2], lw[3]);
            }
        }
        __syncthreads();

        bf16x8 ah[4], al[4], bh[4], bl[4];
#pragma unroll
        for (int i = 0; i < 4; ++i) {
            ah[i] = *(const bf16x8*)&Qh[lg][t_off + i * 16 + l15][0];
            al[i] = *(const bf16x8*)&Ql[lg][t_off + i * 16 + l15][0];
        }
#pragma unroll
        for (int j = 0; j < 4; ++j) {
            bh[j] = *(const bf16x8*)&Xh[lg][s_off + j * 16 + l15][0];
            bl[j] = *(const bf16x8*)&Xl[lg][s_off + j * 16 + l15][0];
        }
#pragma unroll
        for (int i = 0; i < 4; ++i)
#pragma unroll
            for (int j = 0; j < 4; ++j) {
                acc[i][j] = __builtin_amdgcn_mfma_f32_16x16x32_bf16(ah[i], bh[j], acc[i][j], 0, 0, 0);
                acc[i][j] = __builtin_amdgcn_mfma_f32_16x16x32_bf16(al[i], bh[j], acc[i][j], 0, 0, 0);
                acc[i][j] = __builtin_amdgcn_mfma_f32_16x16x32_bf16(ah[i], bl[j], acc[i][j], 0, 0, 0);
            }
    }

    // epilogue: C/D layout col = lane&15 (s), row = (lane>>4)*4 + reg (t)
    float* base = attn + (size_t)b * T_DIM * T_DIM;
#pragma unroll
    for (int i = 0; i < 4; ++i)
#pragma unroll
        for (int j = 0; j < 4; ++j)
#pragma unroll
            for (int r = 0; r < 4; ++r) {
                int t = t0 + t_off + i * 16 + lg * 4 + r;
                int s = s0 + s_off + j * 16 + l15;
                base[(size_t)t * T_DIM + s] = acc[i][j][r];
            }
}

// ---------------- Kernel 4: in-place masked softmax per (b,t) row ----------------
__global__ __launch_bounds__(256) void k_softmax(float* __restrict__ attn) {
    const int row = blockIdx.x;
    const int t = row & (T_DIM - 1);
    float* p = attn + (size_t)row * T_DIM;
    const int tid = threadIdx.x;
    const int n = (t >= 2) ? t : 0;
    __shared__ float red[4];

    if (n == 0) {
        const float4 z = {0.f, 0.f, 0.f, 0.f};
        for (int s = tid * 4; s < T_DIM; s += 1024) *(float4*)&p[s] = z;
        return;
    }

    float m = -INFINITY;
    for (int s = tid; s < n; s += 256) m = fmaxf(m, p[s]);
#pragma unroll
    for (int off = 32; off >= 1; off >>= 1) m = fmaxf(m, __shfl_xor(m, off));
    if ((tid & 63) == 0) red[tid >> 6] = m;
    __syncthreads();
    m = fmaxf(fmaxf(red[0], red[1]), fmaxf(red[2], red[3]));
    __syncthreads();

    float sum = 0.f;
    for (int s = tid; s < n; s += 256) sum += expf(p[s] - m);
#pragma unroll
    for (int off = 32; off >= 1; off >>= 1) sum += __shfl_xor(sum, off);
    if ((tid & 63) == 0) red[tid >> 6] = sum;
    __syncthreads();
    sum = red[0] + red[1] + red[2] + red[3];
    const float inv = 1.f / sum;

    for (int s = tid * 4; s < T_DIM; s += 1024) {
        float4 o = {0.f, 0.f, 0.f, 0.f};
        if (s + 3 < n) {
            float4 v = *(float4*)&p[s];
            o.x = expf(v.x - m) * inv;
            o.y = expf(v.y - m) * inv;
            o.z = expf(v.z - m) * inv;
            o.w = expf(v.w - m) * inv;
        } else if (s < n) {
            float tmp[4] = {0.f, 0.f, 0.f, 0.f};
            for (int j = 0; j < 4; ++j)
                if (s + j < n) tmp[j] = expf(p[s + j] - m) * inv;
            o.x = tmp[0]; o.y = tmp[1]; o.z = tmp[2]; o.w = tmp[3];
        }
        *(float4*)&p[s] = o;
    }
}

extern "C" void kernel_launch(void* const* d_in, const int* in_sizes, int n_in,
                              void* d_out, int out_size, void* d_ws, size_t ws_size,
                              hipStream_t stream) {
    const float* inputs   = (const float*)d_in[0];   // [T,B,H]
    const float* rand_ctx = (const float*)d_in[1];   // [T,B,H]
    const float* W        = (const float*)d_in[2];   // [H,H]
    float* out  = (float*)d_out;
    float* attn = out + (size_t)T_DIM * B_DIM * 2 * H_DIM;
    float* Q    = (float*)d_ws;                      // 64 MB fp32 (proven to fit)

    k_results<<<dim3((T_DIM * B_DIM * 256) / 256), dim3(256), 0, stream>>>(
        (const float4*)inputs, (const float4*)rand_ctx, (float4*)out);

    k_qgemm<<<dim3((T_DIM * B_DIM) / 64, H_DIM / 64), dim3(256), 0, stream>>>(inputs, W, Q);

    k_scores_mfma<<<dim3(T_DIM / 128, T_DIM / 128, B_DIM), dim3(256), 0, stream>>>(Q, inputs, attn);

    k_softmax<<<dim3(B_DIM * T_DIM), dim3(256), 0, stream>>>(attn);
}